// Round 5
// baseline (38.691 us; speedup 1.0000x reference)
//
#include <hip/hip_runtime.h>

// Direct-Form-II biquad over [B=64][T=262144] as a SINGLE-PASS decoupled-
// lookback affine scan.
//   v[t+1] = A v[t] + c x[t],  A = [[-a1,1],[-a2,0]],  out[t] = b0 x[t] + v0[t]
// 4096 blocks; block g: batch b=g>>6, chain pos k=g&63, tile = 4096 samples.
// LDS 19.5 KB/block -> 8 blocks/CU (100% wave occupancy) for latency hiding.
// Sync is fence-free: aggregate (v0,v1) packed in one 64-bit word, published
// with a RELAXED agent atomic; readers spin until word != SENTINEL (negative
// NaN pattern unproducible by this stable filter: |a1|,|a2| < 0.5).

constexpr int BATCH = 64;
constexpr int T_LEN = 262144;
constexpr int TPB   = 256;            // threads per block
constexpr int LPT   = 16;             // samples per thread
constexpr int TILE  = TPB * LPT;      // 4096 samples per block
constexpr int NBPB  = T_LEN / TILE;   // 64 blocks per batch chain
constexpr int NB    = BATCH * NBPB;   // 4096 blocks

#define SENTINEL 0xFFF00001FFF00001ULL

#define MATSQ(m00, m01, m10, m11)                                  \
    {                                                              \
        float n00 = fmaf(m00, m00, m01 * m10);                     \
        float n01 = fmaf(m00, m01, m01 * m11);                     \
        float n10 = fmaf(m10, m00, m11 * m10);                     \
        float n11 = fmaf(m10, m01, m11 * m11);                     \
        m00 = n00; m01 = n01; m10 = n10; m11 = n11;                \
    }

__device__ __forceinline__ unsigned long long pack2(float a, float b) {
    return (unsigned long long)__float_as_uint(a) |
           ((unsigned long long)__float_as_uint(b) << 32);
}

__global__ __launch_bounds__(256) void init_aggs(unsigned long long* __restrict__ aggs) {
    int i = blockIdx.x * 256 + threadIdx.x;
    if (i < NB) aggs[i] = SENTINEL;
}

__global__ __launch_bounds__(TPB) void biquad_lookback(
    const float* __restrict__ x, float* __restrict__ out,
    unsigned long long* __restrict__ aggs,
    const float* __restrict__ pb0, const float* __restrict__ pb1,
    const float* __restrict__ pb2, const float* __restrict__ pa1,
    const float* __restrict__ pa2)
{
    __shared__ float lds[TPB][LPT + 1];     // padded tile: 17,408 B
    __shared__ float sp0[TPB], sp1[TPB];    // scan scratch: 2,048 B

    const int tid  = threadIdx.x;
    const int lane = tid & 63;
    const int g    = blockIdx.x;
    const int b    = g >> 6;                // batch
    const int k    = g & (NBPB - 1);        // chain position

    const float b0 = *pb0, b1 = *pb1, b2 = *pb2;
    const float a1 = *pa1, a2 = *pa2;
    const float na1 = -a1, na2 = -a2;

    // ---- stage tile: 4 coalesced float4 loads per thread ----
    const size_t base = (size_t)b * T_LEN + (size_t)k * TILE;
    const float4* src = reinterpret_cast<const float4*>(x + base);
#pragma unroll
    for (int it = 0; it < TILE / (TPB * 4); ++it) {
        int idx = it * TPB + tid;
        float4 v = src[idx];
        int e = idx * 4, c = e >> 4, t = e & 15;
        lds[c][t] = v.x; lds[c][t + 1] = v.y;
        lds[c][t + 2] = v.z; lds[c][t + 3] = v.w;
    }
    __syncthreads();

    // ---- per-thread zero-init chunk scan (row tid) ----
    float p0 = 0.f, p1 = 0.f;
#pragma unroll
    for (int t = 0; t < LPT; ++t) {
        float xv = lds[tid][t];
        float o  = fmaf(xv, b0, p0);
        float n0 = fmaf(na1, o, fmaf(xv, b1, p1));
        p1 = fmaf(na2, o, xv * b2);
        p0 = n0;
    }

    // ---- block-internal affine scan over 256 thread-carries ----
    // M = A^LPT = A^16 (4 squarings from A)
    float m00 = -a1, m01 = 1.f, m10 = -a2, m11 = 0.f;
#pragma unroll
    for (int s = 0; s < 4; ++s) MATSQ(m00, m01, m10, m11);

    float w00 = m00, w01 = m01, w10 = m10, w11 = m11;
    for (int d = 1; d < 64; d <<= 1) {          // in-wave rounds
        float o0 = __shfl_up(p0, d);
        float o1 = __shfl_up(p1, d);
        if (lane >= d) {
            p0 = fmaf(w00, o0, fmaf(w01, o1, p0));
            p1 = fmaf(w10, o0, fmaf(w11, o1, p1));
        }
        MATSQ(w00, w01, w10, w11);
    }
    for (int d = 64; d < 256; d <<= 1) {        // cross-wave rounds
        sp0[tid] = p0; sp1[tid] = p1;
        __syncthreads();
        float o0 = 0.f, o1 = 0.f;
        const bool has = (tid >= d);
        if (has) { o0 = sp0[tid - d]; o1 = sp1[tid - d]; }
        __syncthreads();
        if (has) {
            p0 = fmaf(w00, o0, fmaf(w01, o1, p0));
            p1 = fmaf(w10, o0, fmaf(w11, o1, p1));
        }
        MATSQ(w00, w01, w10, w11);
    }

    sp0[tid] = p0; sp1[tid] = p1;
    __syncthreads();
    const float agg0 = sp0[TPB - 1], agg1 = sp1[TPB - 1];  // block aggregate
    float q0 = 0.f, q1 = 0.f;                               // excl. prefix
    if (tid > 0) { q0 = sp0[tid - 1]; q1 = sp1[tid - 1]; }

    // ---- publish aggregate: ONE relaxed 64-bit atomic (no fences) ----
    if (tid == 0) {
        __hip_atomic_store(&aggs[g], pack2(agg0, agg1),
                           __ATOMIC_RELAXED, __HIP_MEMORY_SCOPE_AGENT);
    }
    __syncthreads();   // sp reads done before sp0[0] reuse below

    // ---- lookback: wave 0 composes all k predecessor aggregates ----
    float s0 = 0.f, s1 = 0.f;
    if (k > 0) {
        if (tid < 64) {
            const int j = k - 1 - lane;          // pred chain position
            float e0 = 0.f, e1 = 0.f;
            if (j >= 0) {
                const unsigned long long* slot = &aggs[(g - 1) - lane];
                unsigned long long d;
                while ((d = __hip_atomic_load(slot, __ATOMIC_RELAXED,
                                              __HIP_MEMORY_SCOPE_AGENT))
                       == SENTINEL)
                    __builtin_amdgcn_s_sleep(2);
                e0 = __uint_as_float((unsigned)d);
                e1 = __uint_as_float((unsigned)(d >> 32));
            }
            // Wb = A^TILE = A^4096 (8 more squarings from M = A^16)
            float t00 = m00, t01 = m01, t10 = m10, t11 = m11;
#pragma unroll
            for (int s = 0; s < 8; ++s) MATSQ(t00, t01, t10, t11);
            // term = Wb^lane * e   (distance-1 = lane; 6 bits suffice)
            float v0 = e0, v1 = e1;
#pragma unroll
            for (int bit = 0; bit < 6; ++bit) {
                if ((lane >> bit) & 1) {
                    float n0 = fmaf(t00, v0, t01 * v1);
                    float n1 = fmaf(t10, v0, t11 * v1);
                    v0 = n0; v1 = n1;
                }
                MATSQ(t00, t01, t10, t11);
            }
            for (int m = 32; m; m >>= 1) {       // wave sum of terms
                v0 += __shfl_xor(v0, m);
                v1 += __shfl_xor(v1, m);
            }
            if (lane == 0) { sp0[0] = v0; sp1[0] = v1; }
        }
        __syncthreads();
        s0 = sp0[0]; s1 = sp1[0];
    }

    // ---- per-thread true start state: v = A^(LPT*tid) * s + q ----
    float v0 = s0, v1 = s1;
    {
        float t00 = m00, t01 = m01, t10 = m10, t11 = m11;  // A^16
#pragma unroll
        for (int bit = 0; bit < 8; ++bit) {
            if ((tid >> bit) & 1) {
                float n0 = fmaf(t00, v0, t01 * v1);
                float n1 = fmaf(t10, v0, t11 * v1);
                v0 = n0; v1 = n1;
            }
            MATSQ(t00, t01, t10, t11);
        }
    }
    v0 += q0; v1 += q1;

    // ---- final recurrence, outputs in-place into the LDS tile ----
#pragma unroll
    for (int t = 0; t < LPT; ++t) {
        float xv = lds[tid][t];
        float o  = fmaf(xv, b0, v0);
        float n0 = fmaf(na1, o, fmaf(xv, b1, v1));
        v1 = fmaf(na2, o, xv * b2);
        v0 = n0;
        lds[tid][t] = o;
    }
    __syncthreads();

    // ---- coalesced store ----
    float4* dst = reinterpret_cast<float4*>(out + base);
#pragma unroll
    for (int it = 0; it < TILE / (TPB * 4); ++it) {
        int idx = it * TPB + tid;
        int e = idx * 4, c = e >> 4, t = e & 15;
        float4 v;
        v.x = lds[c][t];     v.y = lds[c][t + 1];
        v.z = lds[c][t + 2]; v.w = lds[c][t + 3];
        dst[idx] = v;
    }
}

extern "C" void kernel_launch(void* const* d_in, const int* in_sizes, int n_in,
                              void* d_out, int out_size, void* d_ws, size_t ws_size,
                              hipStream_t stream) {
    const float* x   = (const float*)d_in[0];
    const float* pb0 = (const float*)d_in[1];
    const float* pb1 = (const float*)d_in[2];
    const float* pb2 = (const float*)d_in[3];
    const float* pa1 = (const float*)d_in[4];
    const float* pa2 = (const float*)d_in[5];
    float* out = (float*)d_out;

    unsigned long long* aggs = (unsigned long long*)d_ws;  // 4096 x u64

    init_aggs<<<(NB + 255) / 256, 256, 0, stream>>>(aggs);
    biquad_lookback<<<NB, TPB, 0, stream>>>(x, out, aggs,
                                            pb0, pb1, pb2, pa1, pa2);
}

// Round 6
// 36.363 us; speedup vs baseline: 1.0640x; 1.0640x over previous
//
#include <hip/hip_runtime.h>

// Direct-Form-II biquad over [B=64][T=262144] as a SINGLE-PASS decoupled-
// lookback affine scan.
//   v[t+1] = A v[t] + c x[t],  A = [[-a1,1],[-a2,0]],  out[t] = b0 x[t] + v0[t]
// 1024 blocks of 512 threads; block g: batch b=g>>4, chain pos k=g&15,
// tile = 16384 samples. LDS 71.7 KB/block -> 2 blocks/CU (16 waves, 50%).
// Sync is fence-free: aggregate (v0,v1) packed in one 64-bit word, published
// with a RELAXED agent atomic; readers spin until word != SENTINEL.
// SENTINEL = 0xFF..FF (negative-NaN pair) so it can be seeded with one
// graph-captured hipMemsetAsync; finite stable-filter arithmetic
// (|a1|,|a2| < 0.5, finite x) can never produce NaN/inf.

constexpr int BATCH = 64;
constexpr int T_LEN = 262144;
constexpr int TPB   = 512;            // threads per block
constexpr int LPT   = 32;             // samples per thread
constexpr int TILE  = TPB * LPT;      // 16384 samples per block
constexpr int NBPB  = T_LEN / TILE;   // 16 blocks per batch chain
constexpr int NB    = BATCH * NBPB;   // 1024 blocks

#define SENTINEL 0xFFFFFFFFFFFFFFFFULL

#define MATSQ(m00, m01, m10, m11)                                  \
    {                                                              \
        float n00 = fmaf(m00, m00, m01 * m10);                     \
        float n01 = fmaf(m00, m01, m01 * m11);                     \
        float n10 = fmaf(m10, m00, m11 * m10);                     \
        float n11 = fmaf(m10, m01, m11 * m11);                     \
        m00 = n00; m01 = n01; m10 = n10; m11 = n11;                \
    }

__device__ __forceinline__ unsigned long long pack2(float a, float b) {
    return (unsigned long long)__float_as_uint(a) |
           ((unsigned long long)__float_as_uint(b) << 32);
}

__global__ __launch_bounds__(TPB) void biquad_lookback(
    const float* __restrict__ x, float* __restrict__ out,
    unsigned long long* __restrict__ aggs,
    const float* __restrict__ pb0, const float* __restrict__ pb1,
    const float* __restrict__ pb2, const float* __restrict__ pa1,
    const float* __restrict__ pa2)
{
    __shared__ float lds[TPB][LPT + 1];     // padded tile: 67,584 B
    __shared__ float sp0[TPB], sp1[TPB];    // scan scratch: 4,096 B

    const int tid  = threadIdx.x;
    const int lane = tid & 63;
    const int g    = blockIdx.x;
    const int b    = g >> 4;                // batch
    const int k    = g & (NBPB - 1);        // chain position

    const float b0 = *pb0, b1 = *pb1, b2 = *pb2;
    const float a1 = *pa1, a2 = *pa2;
    const float na1 = -a1, na2 = -a2;

    // ---- stage tile: 8 coalesced float4 loads per thread ----
    const size_t base = (size_t)b * T_LEN + (size_t)k * TILE;
    const float4* src = reinterpret_cast<const float4*>(x + base);
#pragma unroll
    for (int it = 0; it < TILE / (TPB * 4); ++it) {
        int idx = it * TPB + tid;
        float4 v = src[idx];
        int e = idx * 4, c = e >> 5, t = e & 31;
        lds[c][t] = v.x; lds[c][t + 1] = v.y;
        lds[c][t + 2] = v.z; lds[c][t + 3] = v.w;
    }
    __syncthreads();

    // ---- per-thread zero-init chunk scan (row tid) ----
    float p0 = 0.f, p1 = 0.f;
#pragma unroll
    for (int t = 0; t < LPT; ++t) {
        float xv = lds[tid][t];
        float o  = fmaf(xv, b0, p0);
        float n0 = fmaf(na1, o, fmaf(xv, b1, p1));
        p1 = fmaf(na2, o, xv * b2);
        p0 = n0;
    }

    // ---- block-internal affine scan over 512 thread-carries ----
    // M = A^LPT = A^32 (5 squarings from A)
    float m00 = -a1, m01 = 1.f, m10 = -a2, m11 = 0.f;
#pragma unroll
    for (int s = 0; s < 5; ++s) MATSQ(m00, m01, m10, m11);

    float w00 = m00, w01 = m01, w10 = m10, w11 = m11;
    for (int d = 1; d < 64; d <<= 1) {          // in-wave rounds
        float o0 = __shfl_up(p0, d);
        float o1 = __shfl_up(p1, d);
        if (lane >= d) {
            p0 = fmaf(w00, o0, fmaf(w01, o1, p0));
            p1 = fmaf(w10, o0, fmaf(w11, o1, p1));
        }
        MATSQ(w00, w01, w10, w11);
    }
    for (int d = 64; d < TPB; d <<= 1) {        // cross-wave rounds (3)
        sp0[tid] = p0; sp1[tid] = p1;
        __syncthreads();
        float o0 = 0.f, o1 = 0.f;
        const bool has = (tid >= d);
        if (has) { o0 = sp0[tid - d]; o1 = sp1[tid - d]; }
        __syncthreads();
        if (has) {
            p0 = fmaf(w00, o0, fmaf(w01, o1, p0));
            p1 = fmaf(w10, o0, fmaf(w11, o1, p1));
        }
        MATSQ(w00, w01, w10, w11);
    }

    sp0[tid] = p0; sp1[tid] = p1;
    __syncthreads();
    const float agg0 = sp0[TPB - 1], agg1 = sp1[TPB - 1];  // block aggregate
    float q0 = 0.f, q1 = 0.f;                               // excl. prefix
    if (tid > 0) { q0 = sp0[tid - 1]; q1 = sp1[tid - 1]; }

    // ---- publish aggregate: ONE relaxed 64-bit atomic (no fences) ----
    if (tid == 0) {
        __hip_atomic_store(&aggs[g], pack2(agg0, agg1),
                           __ATOMIC_RELAXED, __HIP_MEMORY_SCOPE_AGENT);
    }
    __syncthreads();   // sp reads done before sp0[0] reuse below

    // ---- lookback: wave 0 composes all k predecessor aggregates ----
    float s0 = 0.f, s1 = 0.f;
    if (k > 0) {
        if (tid < 64) {
            const int j = k - 1 - lane;          // pred chain position
            float e0 = 0.f, e1 = 0.f;
            if (j >= 0) {
                const unsigned long long* slot = &aggs[(g - 1) - lane];
                unsigned long long d;
                while ((d = __hip_atomic_load(slot, __ATOMIC_RELAXED,
                                              __HIP_MEMORY_SCOPE_AGENT))
                       == SENTINEL)
                    __builtin_amdgcn_s_sleep(2);
                e0 = __uint_as_float((unsigned)d);
                e1 = __uint_as_float((unsigned)(d >> 32));
            }
            // Wb = A^TILE = A^16384 (9 more squarings from M = A^32)
            float t00 = m00, t01 = m01, t10 = m10, t11 = m11;
#pragma unroll
            for (int s = 0; s < 9; ++s) MATSQ(t00, t01, t10, t11);
            // term = Wb^lane * e   (distance = lane; k<16 -> 4 bits)
            float v0 = e0, v1 = e1;
#pragma unroll
            for (int bit = 0; bit < 4; ++bit) {
                if ((lane >> bit) & 1) {
                    float n0 = fmaf(t00, v0, t01 * v1);
                    float n1 = fmaf(t10, v0, t11 * v1);
                    v0 = n0; v1 = n1;
                }
                MATSQ(t00, t01, t10, t11);
            }
            for (int m = 32; m; m >>= 1) {       // wave sum of terms
                v0 += __shfl_xor(v0, m);
                v1 += __shfl_xor(v1, m);
            }
            if (lane == 0) { sp0[0] = v0; sp1[0] = v1; }
        }
        __syncthreads();
        s0 = sp0[0]; s1 = sp1[0];
    }

    // ---- per-thread true start state: v = A^(LPT*tid) * s + q ----
    float v0 = s0, v1 = s1;
    {
        float t00 = m00, t01 = m01, t10 = m10, t11 = m11;  // A^32
#pragma unroll
        for (int bit = 0; bit < 9; ++bit) {                // tid < 512
            if ((tid >> bit) & 1) {
                float n0 = fmaf(t00, v0, t01 * v1);
                float n1 = fmaf(t10, v0, t11 * v1);
                v0 = n0; v1 = n1;
            }
            MATSQ(t00, t01, t10, t11);
        }
    }
    v0 += q0; v1 += q1;

    // ---- final recurrence, outputs in-place into the LDS tile ----
#pragma unroll
    for (int t = 0; t < LPT; ++t) {
        float xv = lds[tid][t];
        float o  = fmaf(xv, b0, v0);
        float n0 = fmaf(na1, o, fmaf(xv, b1, v1));
        v1 = fmaf(na2, o, xv * b2);
        v0 = n0;
        lds[tid][t] = o;
    }
    __syncthreads();

    // ---- coalesced store ----
    float4* dst = reinterpret_cast<float4*>(out + base);
#pragma unroll
    for (int it = 0; it < TILE / (TPB * 4); ++it) {
        int idx = it * TPB + tid;
        int e = idx * 4, c = e >> 5, t = e & 31;
        float4 v;
        v.x = lds[c][t];     v.y = lds[c][t + 1];
        v.z = lds[c][t + 2]; v.w = lds[c][t + 3];
        dst[idx] = v;
    }
}

extern "C" void kernel_launch(void* const* d_in, const int* in_sizes, int n_in,
                              void* d_out, int out_size, void* d_ws, size_t ws_size,
                              hipStream_t stream) {
    const float* x   = (const float*)d_in[0];
    const float* pb0 = (const float*)d_in[1];
    const float* pb1 = (const float*)d_in[2];
    const float* pb2 = (const float*)d_in[3];
    const float* pa1 = (const float*)d_in[4];
    const float* pa2 = (const float*)d_in[5];
    float* out = (float*)d_out;

    unsigned long long* aggs = (unsigned long long*)d_ws;  // 1024 x u64

    // seed sentinels (all-0xFF) with a graph-capturable async memset
    hipMemsetAsync(aggs, 0xFF, NB * sizeof(unsigned long long), stream);
    biquad_lookback<<<NB, TPB, 0, stream>>>(x, out, aggs,
                                            pb0, pb1, pb2, pa1, pa2);
}

// Round 7
// 35.303 us; speedup vs baseline: 1.0960x; 1.0300x over previous
//
#include <hip/hip_runtime.h>

// Direct-Form-II biquad over [B=64][T=262144] as a SINGLE-PASS decoupled-
// lookback affine scan.  v[t+1] = A v[t] + c x[t],  A = [[-a1,1],[-a2,0]],
// c = [b1-a1*b0, b2-a2*b0],  out[t] = b0 x[t] + v0[t].
// Round-4 geometry (best measured): 2048 blocks x 256 thr, tile 8192, chain 32.
// VALU-reduction round: x kept in registers (no pass-2 LDS reads), pass 1 is a
// 4-step composed update (3 fma/sample), pass 2 is Direct-Form-I (5 fma/sample).
// Fence-free sync: aggregate packed in one u64, RELAXED agent atomics, sentinel
// = 0xFF..FF (NaN pair; unproducible by finite stable-filter arithmetic),
// seeded by graph-capturable hipMemsetAsync.

constexpr int BATCH = 64;
constexpr int T_LEN = 262144;
constexpr int TPB   = 256;            // threads per block
constexpr int LPT   = 32;             // samples per thread
constexpr int TILE  = TPB * LPT;      // 8192 samples per block
constexpr int NBPB  = T_LEN / TILE;   // 32 blocks per batch chain
constexpr int NB    = BATCH * NBPB;   // 2048 blocks

#define SENTINEL 0xFFFFFFFFFFFFFFFFULL

#define MATSQ(m00, m01, m10, m11)                                  \
    {                                                              \
        float n00 = fmaf(m00, m00, m01 * m10);                     \
        float n01 = fmaf(m00, m01, m01 * m11);                     \
        float n10 = fmaf(m10, m00, m11 * m10);                     \
        float n11 = fmaf(m10, m01, m11 * m11);                     \
        m00 = n00; m01 = n01; m10 = n10; m11 = n11;                \
    }

__device__ __forceinline__ unsigned long long pack2(float a, float b) {
    return (unsigned long long)__float_as_uint(a) |
           ((unsigned long long)__float_as_uint(b) << 32);
}

__global__ __launch_bounds__(TPB, 4) void biquad_lookback(
    const float* __restrict__ x, float* __restrict__ out,
    unsigned long long* __restrict__ aggs,
    const float* __restrict__ pb0, const float* __restrict__ pb1,
    const float* __restrict__ pb2, const float* __restrict__ pa1,
    const float* __restrict__ pa2)
{
    __shared__ float lds[TPB][LPT + 1];     // padded tile: 33,792 B
    __shared__ float sp0[TPB], sp1[TPB];    // scan scratch: 2,048 B

    const int tid  = threadIdx.x;
    const int lane = tid & 63;
    const int g    = blockIdx.x;
    const int b    = g >> 5;                // batch
    const int k    = g & (NBPB - 1);        // chain position

    const float b0 = *pb0, b1 = *pb1, b2 = *pb2;
    const float a1 = *pa1, a2 = *pa2;
    const float na1 = -a1, na2 = -a2;

    // ---- composed constants (overlap with global-load latency) ----
    // c = [b1-a1*b0, b2-a2*b0];  k1=Ac, k2=A^2 c, k3=A^3 c;  q=A^4
    const float c0 = fmaf(na1, b0, b1), c1 = fmaf(na2, b0, b2);
    float A00 = na1, A01 = 1.f, A10 = na2, A11 = 0.f;
    const float k1_0 = fmaf(A00, c0, A01 * c1);
    const float k1_1 = fmaf(A10, c0, A11 * c1);
    float B00 = A00, B01 = A01, B10 = A10, B11 = A11;
    MATSQ(B00, B01, B10, B11);                           // A^2
    const float k2_0 = fmaf(B00, c0, B01 * c1);
    const float k2_1 = fmaf(B10, c0, B11 * c1);
    const float k3_0 = fmaf(B00, k1_0, B01 * k1_1);
    const float k3_1 = fmaf(B10, k1_0, B11 * k1_1);
    float q00 = B00, q01 = B01, q10 = B10, q11 = B11;
    MATSQ(q00, q01, q10, q11);                           // A^4

    // ---- stage tile: 8 coalesced float4 loads per thread ----
    const size_t base = (size_t)b * T_LEN + (size_t)k * TILE;
    const float4* src = reinterpret_cast<const float4*>(x + base);
#pragma unroll
    for (int it = 0; it < 8; ++it) {
        int idx = it * TPB + tid;
        float4 v = src[idx];
        int e = idx * 4, c = e >> 5, t = e & 31;
        lds[c][t] = v.x; lds[c][t + 1] = v.y;
        lds[c][t + 2] = v.z; lds[c][t + 3] = v.w;
    }
    __syncthreads();

    // ---- pull row into registers; pass 1 = 4-step composed carry ----
    float xv[LPT];
#pragma unroll
    for (int t = 0; t < LPT; ++t) xv[t] = lds[tid][t];

    float p0 = 0.f, p1 = 0.f;
#pragma unroll
    for (int i = 0; i < LPT / 4; ++i) {
        float xa = xv[4 * i], xb = xv[4 * i + 1];
        float xc = xv[4 * i + 2], xd = xv[4 * i + 3];
        float n0 = fmaf(q00, p0, fmaf(q01, p1,
                   fmaf(k3_0, xa, fmaf(k2_0, xb, fmaf(k1_0, xc, c0 * xd)))));
        float n1 = fmaf(q10, p0, fmaf(q11, p1,
                   fmaf(k3_1, xa, fmaf(k2_1, xb, fmaf(k1_1, xc, c1 * xd)))));
        p0 = n0; p1 = n1;
    }

    // ---- block-internal affine scan over 256 thread-carries ----
    // M = A^32 (3 squarings from A^4)
    float m00 = q00, m01 = q01, m10 = q10, m11 = q11;
#pragma unroll
    for (int s = 0; s < 3; ++s) MATSQ(m00, m01, m10, m11);

    float w00 = m00, w01 = m01, w10 = m10, w11 = m11;
    for (int d = 1; d < 64; d <<= 1) {          // in-wave rounds
        float o0 = __shfl_up(p0, d);
        float o1 = __shfl_up(p1, d);
        if (lane >= d) {
            p0 = fmaf(w00, o0, fmaf(w01, o1, p0));
            p1 = fmaf(w10, o0, fmaf(w11, o1, p1));
        }
        MATSQ(w00, w01, w10, w11);
    }
    for (int d = 64; d < TPB; d <<= 1) {        // cross-wave rounds
        sp0[tid] = p0; sp1[tid] = p1;
        __syncthreads();
        float o0 = 0.f, o1 = 0.f;
        const bool has = (tid >= d);
        if (has) { o0 = sp0[tid - d]; o1 = sp1[tid - d]; }
        __syncthreads();
        if (has) {
            p0 = fmaf(w00, o0, fmaf(w01, o1, p0));
            p1 = fmaf(w10, o0, fmaf(w11, o1, p1));
        }
        MATSQ(w00, w01, w10, w11);
    }

    sp0[tid] = p0; sp1[tid] = p1;
    __syncthreads();
    const float agg0 = sp0[TPB - 1], agg1 = sp1[TPB - 1];  // block aggregate
    float e0x = 0.f, e1x = 0.f;                             // excl. prefix
    if (tid > 0) { e0x = sp0[tid - 1]; e1x = sp1[tid - 1]; }

    // ---- publish aggregate: ONE relaxed 64-bit atomic (no fences) ----
    if (tid == 0) {
        __hip_atomic_store(&aggs[g], pack2(agg0, agg1),
                           __ATOMIC_RELAXED, __HIP_MEMORY_SCOPE_AGENT);
    }
    __syncthreads();   // sp reads done before sp0[0] reuse below

    // ---- lookback: wave 0 composes all k predecessor aggregates ----
    float s0 = 0.f, s1 = 0.f;
    if (k > 0) {
        if (tid < 64) {
            const int j = k - 1 - lane;          // pred chain position
            float e0 = 0.f, e1 = 0.f;
            if (j >= 0) {
                const unsigned long long* slot = &aggs[(g - 1) - lane];
                unsigned long long d;
                while ((d = __hip_atomic_load(slot, __ATOMIC_RELAXED,
                                              __HIP_MEMORY_SCOPE_AGENT))
                       == SENTINEL)
                    __builtin_amdgcn_s_sleep(2);
                e0 = __uint_as_float((unsigned)d);
                e1 = __uint_as_float((unsigned)(d >> 32));
            }
            // Wb = A^TILE = A^8192 (8 more squarings from M = A^32)
            float t00 = m00, t01 = m01, t10 = m10, t11 = m11;
#pragma unroll
            for (int s = 0; s < 8; ++s) MATSQ(t00, t01, t10, t11);
            // term = Wb^lane * e   (distance = lane; k<32 -> 5 bits)
            float v0 = e0, v1 = e1;
#pragma unroll
            for (int bit = 0; bit < 5; ++bit) {
                if ((lane >> bit) & 1) {
                    float n0 = fmaf(t00, v0, t01 * v1);
                    float n1 = fmaf(t10, v0, t11 * v1);
                    v0 = n0; v1 = n1;
                }
                MATSQ(t00, t01, t10, t11);
            }
            for (int m = 32; m; m >>= 1) {       // wave sum of terms
                v0 += __shfl_xor(v0, m);
                v1 += __shfl_xor(v1, m);
            }
            if (lane == 0) { sp0[0] = v0; sp1[0] = v1; }
        }
        __syncthreads();
        s0 = sp0[0]; s1 = sp1[0];
    }

    // ---- per-thread true start state: v = A^(32*tid) * s + excl ----
    float v0 = s0, v1 = s1;
    {
        float t00 = m00, t01 = m01, t10 = m10, t11 = m11;  // A^32
#pragma unroll
        for (int bit = 0; bit < 8; ++bit) {                // tid < 256
            if ((tid >> bit) & 1) {
                float n0 = fmaf(t00, v0, t01 * v1);
                float n1 = fmaf(t10, v0, t11 * v1);
                v0 = n0; v1 = n1;
            }
            MATSQ(t00, t01, t10, t11);
        }
    }
    v0 += e0x; v1 += e1x;

    // ---- pass 2: Direct-Form-I from register x, outputs into LDS ----
    // seed out_0, out_1 via DF-II from the true start state
    float o2 = fmaf(xv[0], b0, v0);                         // out_0
    float vn0 = fmaf(na1, o2, fmaf(xv[0], b1, v1));         // v0 at t=1
    float o1 = fmaf(xv[1], b0, vn0);                        // out_1
    lds[tid][0] = o2; lds[tid][1] = o1;
#pragma unroll
    for (int t = 2; t < LPT; ++t) {
        float acc = fmaf(b1, xv[t - 1], fmaf(b2, xv[t - 2], na2 * o2));
        float o   = fmaf(b0, xv[t], fmaf(na1, o1, acc));
        lds[tid][t] = o;
        o2 = o1; o1 = o;
    }
    __syncthreads();

    // ---- coalesced store ----
    float4* dst = reinterpret_cast<float4*>(out + base);
#pragma unroll
    for (int it = 0; it < 8; ++it) {
        int idx = it * TPB + tid;
        int e = idx * 4, c = e >> 5, t = e & 31;
        float4 v;
        v.x = lds[c][t];     v.y = lds[c][t + 1];
        v.z = lds[c][t + 2]; v.w = lds[c][t + 3];
        dst[idx] = v;
    }
}

extern "C" void kernel_launch(void* const* d_in, const int* in_sizes, int n_in,
                              void* d_out, int out_size, void* d_ws, size_t ws_size,
                              hipStream_t stream) {
    const float* x   = (const float*)d_in[0];
    const float* pb0 = (const float*)d_in[1];
    const float* pb1 = (const float*)d_in[2];
    const float* pb2 = (const float*)d_in[3];
    const float* pa1 = (const float*)d_in[4];
    const float* pa2 = (const float*)d_in[5];
    float* out = (float*)d_out;

    unsigned long long* aggs = (unsigned long long*)d_ws;  // 2048 x u64

    // seed sentinels (all-0xFF) with a graph-capturable async memset
    hipMemsetAsync(aggs, 0xFF, NB * sizeof(unsigned long long), stream);
    biquad_lookback<<<NB, TPB, 0, stream>>>(x, out, aggs,
                                            pb0, pb1, pb2, pa1, pa2);
}

// Round 9
// 34.048 us; speedup vs baseline: 1.1364x; 1.0369x over previous
//
#include <hip/hip_runtime.h>

// Direct-Form-II biquad over [B=64][T=262144] as a SINGLE-PASS decoupled-
// lookback affine scan.  v[t+1] = A v[t] + c x[t],  A = [[-a1,1],[-a2,0]],
// c = [b1-a1*b0, b2-a2*b0],  out[t] = b0 x[t] + v0[t].
// Round-7 kernel + ONE change: non-temporal final stores (out is write-once,
// never re-read) so the 64 MB of output writes don't evict x from L2/L3.
// x (64 MB) then stays Infinity-Cache-resident across graph replays.

constexpr int BATCH = 64;
constexpr int T_LEN = 262144;
constexpr int TPB   = 256;            // threads per block
constexpr int LPT   = 32;             // samples per thread
constexpr int TILE  = TPB * LPT;      // 8192 samples per block
constexpr int NBPB  = T_LEN / TILE;   // 32 blocks per batch chain
constexpr int NB    = BATCH * NBPB;   // 2048 blocks

typedef float vfloat4 __attribute__((ext_vector_type(4)));  // native vec for NT store

#define SENTINEL 0xFFFFFFFFFFFFFFFFULL

#define MATSQ(m00, m01, m10, m11)                                  \
    {                                                              \
        float n00 = fmaf(m00, m00, m01 * m10);                     \
        float n01 = fmaf(m00, m01, m01 * m11);                     \
        float n10 = fmaf(m10, m00, m11 * m10);                     \
        float n11 = fmaf(m10, m01, m11 * m11);                     \
        m00 = n00; m01 = n01; m10 = n10; m11 = n11;                \
    }

__device__ __forceinline__ unsigned long long pack2(float a, float b) {
    return (unsigned long long)__float_as_uint(a) |
           ((unsigned long long)__float_as_uint(b) << 32);
}

__global__ __launch_bounds__(TPB, 4) void biquad_lookback(
    const float* __restrict__ x, float* __restrict__ out,
    unsigned long long* __restrict__ aggs,
    const float* __restrict__ pb0, const float* __restrict__ pb1,
    const float* __restrict__ pb2, const float* __restrict__ pa1,
    const float* __restrict__ pa2)
{
    __shared__ float lds[TPB][LPT + 1];     // padded tile: 33,792 B
    __shared__ float sp0[TPB], sp1[TPB];    // scan scratch: 2,048 B

    const int tid  = threadIdx.x;
    const int lane = tid & 63;
    const int g    = blockIdx.x;
    const int b    = g >> 5;                // batch
    const int k    = g & (NBPB - 1);        // chain position

    const float b0 = *pb0, b1 = *pb1, b2 = *pb2;
    const float a1 = *pa1, a2 = *pa2;
    const float na1 = -a1, na2 = -a2;

    // ---- composed constants (overlap with global-load latency) ----
    // c = [b1-a1*b0, b2-a2*b0];  k1=Ac, k2=A^2 c, k3=A^3 c;  q=A^4
    const float c0 = fmaf(na1, b0, b1), c1 = fmaf(na2, b0, b2);
    float A00 = na1, A01 = 1.f, A10 = na2, A11 = 0.f;
    const float k1_0 = fmaf(A00, c0, A01 * c1);
    const float k1_1 = fmaf(A10, c0, A11 * c1);
    float B00 = A00, B01 = A01, B10 = A10, B11 = A11;
    MATSQ(B00, B01, B10, B11);                           // A^2
    const float k2_0 = fmaf(B00, c0, B01 * c1);
    const float k2_1 = fmaf(B10, c0, B11 * c1);
    const float k3_0 = fmaf(B00, k1_0, B01 * k1_1);
    const float k3_1 = fmaf(B10, k1_0, B11 * k1_1);
    float q00 = B00, q01 = B01, q10 = B10, q11 = B11;
    MATSQ(q00, q01, q10, q11);                           // A^4

    // ---- stage tile: 8 coalesced float4 loads per thread ----
    const size_t base = (size_t)b * T_LEN + (size_t)k * TILE;
    const float4* src = reinterpret_cast<const float4*>(x + base);
#pragma unroll
    for (int it = 0; it < 8; ++it) {
        int idx = it * TPB + tid;
        float4 v = src[idx];
        int e = idx * 4, c = e >> 5, t = e & 31;
        lds[c][t] = v.x; lds[c][t + 1] = v.y;
        lds[c][t + 2] = v.z; lds[c][t + 3] = v.w;
    }
    __syncthreads();

    // ---- pull row into registers; pass 1 = 4-step composed carry ----
    float xv[LPT];
#pragma unroll
    for (int t = 0; t < LPT; ++t) xv[t] = lds[tid][t];

    float p0 = 0.f, p1 = 0.f;
#pragma unroll
    for (int i = 0; i < LPT / 4; ++i) {
        float xa = xv[4 * i], xb = xv[4 * i + 1];
        float xc = xv[4 * i + 2], xd = xv[4 * i + 3];
        float n0 = fmaf(q00, p0, fmaf(q01, p1,
                   fmaf(k3_0, xa, fmaf(k2_0, xb, fmaf(k1_0, xc, c0 * xd)))));
        float n1 = fmaf(q10, p0, fmaf(q11, p1,
                   fmaf(k3_1, xa, fmaf(k2_1, xb, fmaf(k1_1, xc, c1 * xd)))));
        p0 = n0; p1 = n1;
    }

    // ---- block-internal affine scan over 256 thread-carries ----
    // M = A^32 (3 squarings from A^4)
    float m00 = q00, m01 = q01, m10 = q10, m11 = q11;
#pragma unroll
    for (int s = 0; s < 3; ++s) MATSQ(m00, m01, m10, m11);

    float w00 = m00, w01 = m01, w10 = m10, w11 = m11;
    for (int d = 1; d < 64; d <<= 1) {          // in-wave rounds
        float o0 = __shfl_up(p0, d);
        float o1 = __shfl_up(p1, d);
        if (lane >= d) {
            p0 = fmaf(w00, o0, fmaf(w01, o1, p0));
            p1 = fmaf(w10, o0, fmaf(w11, o1, p1));
        }
        MATSQ(w00, w01, w10, w11);
    }
    for (int d = 64; d < TPB; d <<= 1) {        // cross-wave rounds
        sp0[tid] = p0; sp1[tid] = p1;
        __syncthreads();
        float o0 = 0.f, o1 = 0.f;
        const bool has = (tid >= d);
        if (has) { o0 = sp0[tid - d]; o1 = sp1[tid - d]; }
        __syncthreads();
        if (has) {
            p0 = fmaf(w00, o0, fmaf(w01, o1, p0));
            p1 = fmaf(w10, o0, fmaf(w11, o1, p1));
        }
        MATSQ(w00, w01, w10, w11);
    }

    sp0[tid] = p0; sp1[tid] = p1;
    __syncthreads();
    const float agg0 = sp0[TPB - 1], agg1 = sp1[TPB - 1];  // block aggregate
    float e0x = 0.f, e1x = 0.f;                             // excl. prefix
    if (tid > 0) { e0x = sp0[tid - 1]; e1x = sp1[tid - 1]; }

    // ---- publish aggregate: ONE relaxed 64-bit atomic (no fences) ----
    if (tid == 0) {
        __hip_atomic_store(&aggs[g], pack2(agg0, agg1),
                           __ATOMIC_RELAXED, __HIP_MEMORY_SCOPE_AGENT);
    }
    __syncthreads();   // sp reads done before sp0[0] reuse below

    // ---- lookback: wave 0 composes all k predecessor aggregates ----
    float s0 = 0.f, s1 = 0.f;
    if (k > 0) {
        if (tid < 64) {
            const int j = k - 1 - lane;          // pred chain position
            float e0 = 0.f, e1 = 0.f;
            if (j >= 0) {
                const unsigned long long* slot = &aggs[(g - 1) - lane];
                unsigned long long d;
                while ((d = __hip_atomic_load(slot, __ATOMIC_RELAXED,
                                              __HIP_MEMORY_SCOPE_AGENT))
                       == SENTINEL)
                    __builtin_amdgcn_s_sleep(2);
                e0 = __uint_as_float((unsigned)d);
                e1 = __uint_as_float((unsigned)(d >> 32));
            }
            // Wb = A^TILE = A^8192 (8 more squarings from M = A^32)
            float t00 = m00, t01 = m01, t10 = m10, t11 = m11;
#pragma unroll
            for (int s = 0; s < 8; ++s) MATSQ(t00, t01, t10, t11);
            // term = Wb^lane * e   (distance = lane; k<32 -> 5 bits)
            float v0 = e0, v1 = e1;
#pragma unroll
            for (int bit = 0; bit < 5; ++bit) {
                if ((lane >> bit) & 1) {
                    float n0 = fmaf(t00, v0, t01 * v1);
                    float n1 = fmaf(t10, v0, t11 * v1);
                    v0 = n0; v1 = n1;
                }
                MATSQ(t00, t01, t10, t11);
            }
            for (int m = 32; m; m >>= 1) {       // wave sum of terms
                v0 += __shfl_xor(v0, m);
                v1 += __shfl_xor(v1, m);
            }
            if (lane == 0) { sp0[0] = v0; sp1[0] = v1; }
        }
        __syncthreads();
        s0 = sp0[0]; s1 = sp1[0];
    }

    // ---- per-thread true start state: v = A^(32*tid) * s + excl ----
    float v0 = s0, v1 = s1;
    {
        float t00 = m00, t01 = m01, t10 = m10, t11 = m11;  // A^32
#pragma unroll
        for (int bit = 0; bit < 8; ++bit) {                // tid < 256
            if ((tid >> bit) & 1) {
                float n0 = fmaf(t00, v0, t01 * v1);
                float n1 = fmaf(t10, v0, t11 * v1);
                v0 = n0; v1 = n1;
            }
            MATSQ(t00, t01, t10, t11);
        }
    }
    v0 += e0x; v1 += e1x;

    // ---- pass 2: Direct-Form-I from register x, outputs into LDS ----
    float o2 = fmaf(xv[0], b0, v0);                         // out_0
    float vn0 = fmaf(na1, o2, fmaf(xv[0], b1, v1));         // v0 at t=1
    float o1 = fmaf(xv[1], b0, vn0);                        // out_1
    lds[tid][0] = o2; lds[tid][1] = o1;
#pragma unroll
    for (int t = 2; t < LPT; ++t) {
        float acc = fmaf(b1, xv[t - 1], fmaf(b2, xv[t - 2], na2 * o2));
        float o   = fmaf(b0, xv[t], fmaf(na1, o1, acc));
        lds[tid][t] = o;
        o2 = o1; o1 = o;
    }
    __syncthreads();

    // ---- coalesced NON-TEMPORAL store (don't evict x from L2/L3) ----
    vfloat4* dst = reinterpret_cast<vfloat4*>(out + base);
#pragma unroll
    for (int it = 0; it < 8; ++it) {
        int idx = it * TPB + tid;
        int e = idx * 4, c = e >> 5, t = e & 31;
        vfloat4 v;
        v.x = lds[c][t];     v.y = lds[c][t + 1];
        v.z = lds[c][t + 2]; v.w = lds[c][t + 3];
        __builtin_nontemporal_store(v, &dst[idx]);
    }
}

extern "C" void kernel_launch(void* const* d_in, const int* in_sizes, int n_in,
                              void* d_out, int out_size, void* d_ws, size_t ws_size,
                              hipStream_t stream) {
    const float* x   = (const float*)d_in[0];
    const float* pb0 = (const float*)d_in[1];
    const float* pb1 = (const float*)d_in[2];
    const float* pb2 = (const float*)d_in[3];
    const float* pa1 = (const float*)d_in[4];
    const float* pa2 = (const float*)d_in[5];
    float* out = (float*)d_out;

    unsigned long long* aggs = (unsigned long long*)d_ws;  // 2048 x u64

    // seed sentinels (all-0xFF) with a graph-capturable async memset
    (void)hipMemsetAsync(aggs, 0xFF, NB * sizeof(unsigned long long), stream);
    biquad_lookback<<<NB, TPB, 0, stream>>>(x, out, aggs,
                                            pb0, pb1, pb2, pa1, pa2);
}